// Round 2
// baseline (789.534 us; speedup 1.0000x reference)
//
#include <hip/hip_runtime.h>

#define NEGF (-1e30f)

constexpr int S = 512;
constexpr int L = 32;

// R7: barrier-free producer/consumer wave specialization.
//   alpha[f][c] = LSE_{j=1..min(64,f+1)} beta[f-j][c] + j*seg[f-j+1,f,c] + (j-1)*diag[c]
//   beta[p][c]  = LSE_prev alpha[p][prev] + T[prev][c],  beta[-1] = 0
// Wave 0 ("chain") runs the serial core alone (j=1,2,3 from registers bm1/bm2 +
// the full matvec) with NO s_barrier: alpha is a (max,sum) register pair; the
// matvec is u_c = Sa*exp(Ma-mxg) (one exp) -> same-wave LDS broadcast -> pure
// FMA dot with E=exp(T) -> beta = mxg + log(dot) (one log).
// Waves 1..3 ("lag") compute LSE partials over j in [4,24],[25,44],[45,64] for
// frame f once chain_done >= f-4 (ring betas available), writing (M,S) to
// part[f&3][w][c].  Chain polls lag_done one frame early so the partial reads
// overlap the previous frame.  All cross-wave sync is LDS counters (volatile +
// workgroup/local fences); lag stalls never touch the chain's critical path.

template <int CTRL>
__device__ __forceinline__ float dppf(float x) {
    return __builtin_bit_cast(float,
        __builtin_amdgcn_update_dpp(0, __builtin_bit_cast(int, x),
                                    CTRL, 0xf, 0xf, true));
}
// reduce over each 32-lane half via xor{1,2,7,15,16}; valid in all lanes.
#define RED32_MAX(v) do { v = fmaxf(v, dppf<0xB1>(v));                      \
                          v = fmaxf(v, dppf<0x4E>(v));                      \
                          v = fmaxf(v, dppf<0x141>(v));                     \
                          v = fmaxf(v, dppf<0x140>(v));                     \
                          v = fmaxf(v, __shfl_xor(v, 16)); } while (0)
#define RED32_ADD(v) do { v += dppf<0xB1>(v); v += dppf<0x4E>(v);           \
                          v += dppf<0x141>(v); v += dppf<0x140>(v);         \
                          v += __shfl_xor(v, 16); } while (0)

// ---------------- lag producer: LSE partial over j = [jb .. jb+nt) per half --
template<int JLO, int NT0, int NT1, int W>
__device__ __forceinline__ void lag_run(const float* __restrict__ segB,
                                        const float* __restrict__ trans,
                                        float* ring,
                                        float (*part)[3][32][2],
                                        volatile int* cnt,
                                        int c, int h, bool lane0)
{
    const float diag_c = trans[c * 33];
    const int nt = h ? NT1 : NT0;              // 10 or 11 terms for this lane
    const int jb = JLO + (h ? NT0 : 0);
    float jfv[11], djv[11];
    int idxA[11], idxB[11];
#pragma unroll
    for (int i = 0; i < 11; ++i) {
        const int jj = (i < nt) ? (jb + i) : jb;   // pad lane dups term 0 addr
        jfv[i] = (float)jj;
        djv[i] = diag_c * (float)(jj - 1);
        // seg element index for frame f: (f*(S+1) - (j-1)*S)*L + c ; starts f=3/4
        idxA[i] = (3 * (S + 1) - (jj - 1) * S) * L + c;
        idxB[i] = idxA[i] + (S + 1) * L;
    }
    float svA[11], svB[11];
    int cd = -1;   // cached chain_done (stale-safe: only underestimates)

#define LAG_PF(sv, idx, fq, MSK) do {                                       \
    _Pragma("unroll")                                                       \
    for (int i = 0; i < 11; ++i) {                                          \
        int e = idx[i];                                                     \
        if (MSK) {                                                          \
            const bool vld = (i < nt) && (jb + i <= (fq) + 1);              \
            e = vld ? e : ((fq) * L + c);   /* safe in-bounds fallback */   \
        }                                                                   \
        sv[i] = segB[e];                                                    \
        idx[i] += 2 * (S + 1) * L;          /* buffer serves every 2nd frame */ \
    }                                                                       \
} while (0)

#define LAG_FRAME(f_, sv, MSK) do {                                         \
    const int ff = (f_);                                                    \
    if (cd < ff - 4) {                                                      \
        do { __builtin_amdgcn_s_sleep(1); cd = cnt[3]; } while (cd < ff - 4); \
    }                                                                       \
    __builtin_amdgcn_fence(__ATOMIC_ACQUIRE, "workgroup", "local");         \
    const int fj = ff - jb;                                                 \
    float tt[11];                                                           \
    _Pragma("unroll")                                                       \
    for (int i = 0; i < 11; ++i) {                                          \
        const float rv = ring[((fj - i) & 63) * 33 + c];                    \
        const float tv = rv + fmaf(sv[i], jfv[i], djv[i]);                  \
        bool vld = (i < nt);                                                \
        if (MSK) vld = vld && (jb + i <= ff + 1);                           \
        tt[i] = vld ? tv : NEGF;                                            \
    }                                                                       \
    float m = fmaxf(fmaxf(fmaxf(fmaxf(tt[0], tt[1]), fmaxf(tt[2], tt[3])),  \
                          fmaxf(fmaxf(tt[4], tt[5]), fmaxf(tt[6], tt[7]))), \
                    fmaxf(fmaxf(tt[8], tt[9]), tt[10]));                    \
    float s = ((__expf(tt[0] - m) + __expf(tt[1] - m)) +                    \
               (__expf(tt[2] - m) + __expf(tt[3] - m))) +                   \
              ((__expf(tt[4] - m) + __expf(tt[5] - m)) +                    \
               (__expf(tt[6] - m) + __expf(tt[7] - m))) +                   \
              ((__expf(tt[8] - m) + __expf(tt[9] - m)) +                    \
               __expf(tt[10] - m));                                         \
    const float m2 = __shfl_xor(m, 32);                                     \
    const float s2 = __shfl_xor(s, 32);                                     \
    const float Mw = fmaxf(m, m2);                                          \
    const float Sw = s * __expf(m - Mw) + s2 * __expf(m2 - Mw);             \
    if (h == 0) *(float2*)&part[ff & 3][W][c][0] = make_float2(Mw, Sw);     \
    asm volatile("s_waitcnt lgkmcnt(0)" ::: "memory");                      \
    if (lane0) cnt[W] = ff;                                                 \
} while (0)

    LAG_PF(svA, idxA, 3, true);
    LAG_PF(svB, idxB, 4, true);
    // masked region: frames 3..62 (j <= f+1 guard; j == f+1 hits ring row 63 = beta[-1] = 0)
    for (int f = 3; f <= 61; f += 2) {
        LAG_FRAME(f, svA, true);      LAG_PF(svA, idxA, f + 2, true);
        LAG_FRAME(f + 1, svB, true);  LAG_PF(svB, idxB, f + 3, true);
    }
    // clean region: frames 63..508
    for (int f = 63; f <= 507; f += 2) {
        LAG_FRAME(f, svA, false);     LAG_PF(svA, idxA, f + 2, false);
        LAG_FRAME(f + 1, svB, false); LAG_PF(svB, idxB, f + 3, false);
    }
    LAG_FRAME(509, svA, false);
    LAG_PF(svA, idxA, 511, false);
    LAG_FRAME(510, svB, false);
    LAG_FRAME(511, svA, false);
#undef LAG_PF
#undef LAG_FRAME
}

__launch_bounds__(256, 1)
__global__ void semicrf_fwd(const float* __restrict__ seg,
                            const float* __restrict__ trans,
                            float* __restrict__ out)
{
    const int t  = threadIdx.x;
    const int b  = blockIdx.x;
    const int c  = t & 31;
    const int h  = (t >> 5) & 1;
    const int wv = t >> 6;

    __shared__ float ring[64 * 33];                   // log-beta; row 63 pre-init 0 = beta[-1]
    __shared__ __align__(16) float part[4][3][32][2]; // lag (M,S) partials, slot = f&3
    __shared__ __align__(16) float ubuf[32];          // chain matvec broadcast buffer
    __shared__ int cnt_s[4];                          // 0..2 lag_done, 3 chain_done

    for (int i = t; i < 4 * 3 * 32; i += 256)
        ((float2*)part)[i] = make_float2(NEGF, 0.f);
    if (t < 32) ring[63 * 33 + t] = 0.f;
    if (t < 3)  cnt_s[t] = 2;
    if (t == 3) cnt_s[3] = -1;
    __syncthreads();   // only barrier in the kernel

    const float* segB  = seg + (size_t)b * S * S * L;
    volatile int* cnt  = cnt_s;

    if (wv == 0) {
        // ---------------- chain wave: the serial core, no barriers ----------
        __builtin_amdgcn_s_setprio(1);
        float E[16];
#pragma unroll
        for (int i = 0; i < 16; ++i)
            E[i] = __expf(trans[(h * 16 + i) * 32 + c]);   // E[prev=h*16+i][c]
        const float diag_c = trans[c * 33];

        // j=1,2,3 seg scalars, prefetch depth 4 (slot = f'&3)
        float s1s[4], s2s[4], s3s[4];
#pragma unroll
        for (int ff = 1; ff <= 4; ++ff) {
            const int st1 = ff, st2 = ff - 1, st3 = (ff - 2 < 0) ? 0 : ff - 2;
            s1s[ff & 3] = segB[(st1 * S + ff) * L + c];
            s2s[ff & 3] = segB[(st2 * S + ff) * L + c];
            s3s[ff & 3] = segB[(st3 * S + ff) * L + c];   // f'=1 garbage, masked by bm2=NEG
        }

        float Ma = segB[c];      // alpha[0] = seg[0,0,c] as (max,sum)
        float Sa = 1.f;
        float bm1 = 0.f;         // beta[-1] = 0
        float bm2 = NEGF;        // beta[-2] (invalid)
        int lmin = 2, l0 = 2, l1 = 2, l2 = 2;

#define CHAIN_FRAME(f_, Q_) do {                                            \
    const int ff = (f_);                                                    \
    if (lmin < ff + 1) {                                                    \
        do { l0 = cnt[0]; l1 = cnt[1]; l2 = cnt[2];                         \
             lmin = min(min(l0, l1), l2); } while (lmin < ff + 1);          \
    }                                                                       \
    __builtin_amdgcn_fence(__ATOMIC_ACQUIRE, "workgroup", "local");         \
    /* phase2: beta[ff] from (Ma,Sa) */                                     \
    float mx = Ma;                                                          \
    RED32_MAX(mx);                                                          \
    const float uu = Sa * __expf(Ma - mx);                                  \
    if (h == 0) ubuf[c] = uu;                                               \
    if (t == 0) cnt[3] = ff - 1;   /* ring row ff-1 completed last frame */ \
    asm volatile("s_waitcnt lgkmcnt(0)" ::: "memory");                      \
    const float4 uA = *(const float4*)&ubuf[h * 16 + 0];                    \
    const float4 uB = *(const float4*)&ubuf[h * 16 + 4];                    \
    const float4 uC = *(const float4*)&ubuf[h * 16 + 8];                    \
    const float4 uD = *(const float4*)&ubuf[h * 16 + 12];                   \
    const float2 P0 = *(const float2*)&part[Q_][0][c][0];                   \
    const float2 P1 = *(const float2*)&part[Q_][1][c][0];                   \
    const float2 P2 = *(const float2*)&part[Q_][2][c][0];                   \
    l0 = cnt[0]; l1 = cnt[1]; l2 = cnt[2];                                  \
    float dA = fmaf(uA.x, E[0],  fmaf(uA.y, E[1],  fmaf(uA.z, E[2],  uA.w * E[3])));  \
    float dB = fmaf(uB.x, E[4],  fmaf(uB.y, E[5],  fmaf(uB.z, E[6],  uB.w * E[7])));  \
    float dC = fmaf(uC.x, E[8],  fmaf(uC.y, E[9],  fmaf(uC.z, E[10], uC.w * E[11]))); \
    float dD = fmaf(uD.x, E[12], fmaf(uD.y, E[13], fmaf(uD.z, E[14], uD.w * E[15]))); \
    float dot = (dA + dB) + (dC + dD);                                      \
    dot += __shfl_xor(dot, 32);                                             \
    const float bb = mx + __logf(dot);                                      \
    if (h == 0) ring[(ff & 63) * 33 + c] = bb;                              \
    /* merge -> alpha[ff+1]; early part independent of bb */                \
    const float t2v = fmaf(2.f, s2s[Q_], bm1 + diag_c);                     \
    const float t3v = fmaf(3.f, s3s[Q_], bm2 + 2.f * diag_c);               \
    const float Mp  = fmaxf(fmaxf(P0.x, P1.x), fmaxf(P2.x, fmaxf(t2v, t3v)));        \
    const float Sp  = P0.y * __expf(P0.x - Mp) + P1.y * __expf(P1.x - Mp)            \
                    + P2.y * __expf(P2.x - Mp)                              \
                    + __expf(t2v - Mp) + __expf(t3v - Mp);                  \
    const float t1v = bb + s1s[Q_];                                         \
    Ma = fmaxf(Mp, t1v);                                                    \
    Sa = fmaf(Sp, __expf(Mp - Ma), __expf(t1v - Ma));                       \
    bm2 = bm1; bm1 = bb;                                                    \
    lmin = min(min(l0, l1), l2);                                            \
    { int fq = ff + 5; if (fq > 511) fq = 511;                              \
      const int bidx = fq * (S + 1) * L + c;                                \
      s1s[Q_] = segB[bidx];                                                 \
      s2s[Q_] = segB[bidx - S * L];                                         \
      s3s[Q_] = segB[bidx - 2 * S * L]; }                                   \
} while (0)

        for (int fb = 0; fb < 508; fb += 4) {
            CHAIN_FRAME(fb + 0, 1);
            CHAIN_FRAME(fb + 1, 2);
            CHAIN_FRAME(fb + 2, 3);
            CHAIN_FRAME(fb + 3, 0);
        }
        CHAIN_FRAME(508, 1);
        CHAIN_FRAME(509, 2);
        CHAIN_FRAME(510, 3);
#undef CHAIN_FRAME
        {   // f = 511: log_z[b] = LSE_c alpha[511][c]
            float mx = Ma;
            RED32_MAX(mx);
            float uu = Sa * __expf(Ma - mx);
            RED32_ADD(uu);
            if (t == 0) out[b] = mx + __logf(uu);
        }
    } else if (wv == 1) {
        lag_run<4, 11, 10, 0>(segB, trans, ring, part, cnt, c, h, (t & 63) == 0);
    } else if (wv == 2) {
        lag_run<25, 10, 10, 1>(segB, trans, ring, part, cnt, c, h, (t & 63) == 0);
    } else {
        lag_run<45, 10, 10, 2>(segB, trans, ring, part, cnt, c, h, (t & 63) == 0);
    }
}

extern "C" void kernel_launch(void* const* d_in, const int* in_sizes, int n_in,
                              void* d_out, int out_size, void* d_ws, size_t ws_size,
                              hipStream_t stream) {
    const float* seg   = (const float*)d_in[0];   // [8, 512, 512, 32] fp32
    const float* trans = (const float*)d_in[1];   // [32, 32] fp32
    float* out = (float*)d_out;                   // [8] fp32
    hipLaunchKernelGGL(semicrf_fwd, dim3(8), dim3(256), 0, stream,
                       seg, trans, out);
}

// Round 4
// 646.168 us; speedup vs baseline: 1.2219x; 1.2219x over previous
//
#include <hip/hip_runtime.h>

#define NEGF (-1e30f)

constexpr int S = 512;
constexpr int L = 32;
constexpr int SL1 = (S + 1) * L;      // seg offset step per frame (element units)
constexpr int SLN = S * L;            // step per j
constexpr int SSL = S * S * L;        // per-batch seg element count (bounds clamp)
constexpr int RSTR = 33;              // ring row stride (floats)
constexpr int RROWS = 128;            // ring rows; beta[p] lives at row (p+1)&127
constexpr int RWRAP = RROWS * RSTR;   // 4224
constexpr int SPIN_CAP = 1 << 20;     // bounded spin: deadlock -> visible failure

// R9 = R8 + OOB fix: decoupled wave specialization.
//   alpha[f][c] = LSE_{j=1..min(64,f+1)} beta[f-j][c] + j*seg[f-j+1,f,c] + (j-1)*diag[c]
//   beta[p][c]  = LSE_prev alpha[p][prev] + T[prev][c],  beta[-1]=0 (ring row 0)
// Wave 0 (chain): j=1..15 from a 14-deep REGISTER beta history; alpha carried as
//   (max,sum); matvec via ONE LDS round trip (u broadcast) per frame; normalizer
//   mx is the PREVIOUS frame's max (defer-max, off-path RED32).  Cross-wave
//   traffic: 1 poll / 4 frames, 1 publish / 4 frames.  Partials prefetched 3
//   frames ahead (pp1/pp2 register pipeline).
// Waves 1-3 (lag): j=16..64 partials in 4-frame batches, stride 12; batch F
//   gated on chain >= F-13, deadline chain F-3 => ~10-frame latency window so
//   lag stalls (HBM, sleep quanta) stay off the chain's path.
// R9 fixes: chain seg refill clamped to [c, SSL) (R8 read 131KB past the tensor
//   at frames 509-510 on batch 7 -> page fault -> container kill).  All spin
//   loops now capped (SPIN_CAP) so any protocol flaw fails visibly, not hangs.

template <int CTRL>
__device__ __forceinline__ float dppf(float x) {
    return __builtin_bit_cast(float,
        __builtin_amdgcn_update_dpp(0, __builtin_bit_cast(int, x),
                                    CTRL, 0xf, 0xf, true));
}
// max over each 32-lane half (all lanes get result); off critical path only.
#define RED32_MAX(v) do { v = fmaxf(v, dppf<0xB1>(v));                      \
                          v = fmaxf(v, dppf<0x4E>(v));                      \
                          v = fmaxf(v, dppf<0x141>(v));                     \
                          v = fmaxf(v, dppf<0x140>(v));                     \
                          v = fmaxf(v, __shfl_xor(v, 16)); } while (0)

// ---------------------------------------------------------------- chain macro
#define CHAIN(ff_, SBUF, DOPOLL, DOPUB) do {                                \
    const int ff = (ff_);                                                   \
    /* off-path: j=2..15 terms (register history) + partial merge prep */   \
    float tj[14];                                                           \
    _Pragma("unroll")                                                       \
    for (int i = 0; i < 14; ++i)                                            \
        tj[i] = bH[i] + fmaf(SBUF[i + 1], (float)(i + 2), dgc[i]);          \
    float Mp = fmaxf(pp1.x, tj[0]);                                         \
    _Pragma("unroll")                                                       \
    for (int i = 1; i < 14; ++i) Mp = fmaxf(Mp, tj[i]);                     \
    float Sp = pp1.y * __expf(pp1.x - Mp);                                  \
    _Pragma("unroll")                                                       \
    for (int i = 0; i < 14; ++i) Sp += __expf(tj[i] - Mp);                  \
    float mxn = Ma;                                                         \
    RED32_MAX(mxn);                    /* max alpha[ff], used NEXT frame */ \
    /* on-path: u broadcast -> dot -> beta[ff] */                           \
    const float uu = Sa * __expf(Ma - mx);                                  \
    if (t < 32) ubuf[c] = uu;                                               \
    const float4 u0 = *(const float4*)&ubuf[0];                             \
    const float4 u1 = *(const float4*)&ubuf[4];                             \
    const float4 u2 = *(const float4*)&ubuf[8];                             \
    const float4 u3 = *(const float4*)&ubuf[12];                            \
    const float4 u4 = *(const float4*)&ubuf[16];                            \
    const float4 u5 = *(const float4*)&ubuf[20];                            \
    const float4 u6 = *(const float4*)&ubuf[24];                            \
    const float4 u7 = *(const float4*)&ubuf[28];                            \
    float d0 = u0.x * E[0];                                                 \
    d0 = fmaf(u0.y, E[1], d0);  d0 = fmaf(u0.z, E[2], d0);                  \
    d0 = fmaf(u0.w, E[3], d0);  d0 = fmaf(u1.x, E[4], d0);                  \
    d0 = fmaf(u1.y, E[5], d0);  d0 = fmaf(u1.z, E[6], d0);                  \
    d0 = fmaf(u1.w, E[7], d0);                                              \
    float d1 = u2.x * E[8];                                                 \
    d1 = fmaf(u2.y, E[9],  d1); d1 = fmaf(u2.z, E[10], d1);                 \
    d1 = fmaf(u2.w, E[11], d1); d1 = fmaf(u3.x, E[12], d1);                 \
    d1 = fmaf(u3.y, E[13], d1); d1 = fmaf(u3.z, E[14], d1);                 \
    d1 = fmaf(u3.w, E[15], d1);                                             \
    float d2 = u4.x * E[16];                                                \
    d2 = fmaf(u4.y, E[17], d2); d2 = fmaf(u4.z, E[18], d2);                 \
    d2 = fmaf(u4.w, E[19], d2); d2 = fmaf(u5.x, E[20], d2);                 \
    d2 = fmaf(u5.y, E[21], d2); d2 = fmaf(u5.z, E[22], d2);                 \
    d2 = fmaf(u5.w, E[23], d2);                                             \
    float d3 = u6.x * E[24];                                                \
    d3 = fmaf(u6.y, E[25], d3); d3 = fmaf(u6.z, E[26], d3);                 \
    d3 = fmaf(u6.w, E[27], d3); d3 = fmaf(u7.x, E[28], d3);                 \
    d3 = fmaf(u7.y, E[29], d3); d3 = fmaf(u7.z, E[30], d3);                 \
    d3 = fmaf(u7.w, E[31], d3);                                             \
    const float dot = (d0 + d1) + (d2 + d3);                                \
    const float bb = mx + __logf(dot);                                      \
    if (t < 32) ring[wadr] = bb;                                            \
    wadr += RSTR; if (wadr >= RWRAP) wadr -= RWRAP;                         \
    /* merge -> alpha[ff+1] */                                              \
    const float t1 = bb + SBUF[0];                                          \
    const float Man = fmaxf(Mp, t1);                                        \
    Sa = fmaf(Sp, __expf(Mp - Man), __expf(t1 - Man));                      \
    Ma = Man;                                                               \
    mx = mxn;                                                               \
    if (DOPUB) {                                                            \
        asm volatile("s_waitcnt lgkmcnt(0)" ::: "memory");                  \
        if (t == 0) cntv[3] = ff;                                           \
    }                                                                       \
    if (DOPOLL) {                                                           \
        const int Fb = ff + 3;                                              \
        if (Fb <= 508) {                                                    \
            volatile int* cw = &cntv[(Fb >> 2) % 3];                        \
            int zz = 0;                                                     \
            while (*cw < Fb && ++zz < SPIN_CAP) {}                          \
            __builtin_amdgcn_fence(__ATOMIC_ACQUIRE, "workgroup", "local"); \
        }                                                                   \
    }                                                                       \
    pp1 = pp2;                                                              \
    pp2 = part[(ff + 3) & 31][c];                                           \
    _Pragma("unroll")                                                       \
    for (int i = 13; i > 0; --i) bH[i] = bH[i - 1];                         \
    bH[0] = bb;                                                             \
    /* refill SBUF with seg column e = ff+3 (used at frame ff+2) */         \
    _Pragma("unroll")                                                       \
    for (int i = 0; i < 15; ++i) {                                          \
        int o = offv[i];                                                    \
        o = (o < (int)c || o >= SSL) ? (int)c : o;   /* OOB clamp (R9 fix) */ \
        SBUF[i] = segB[o];                                                  \
        offv[i] += SL1;                                                     \
    }                                                                       \
} while (0)

// ------------------------------------------------------------------ lag macros
#define LLOAD(BUF) do {                                                     \
    _Pragma("unroll")                                                       \
    for (int i = 0; i < 25; ++i) {                                          \
        int o = offs[i];                                                    \
        o = (o < (int)c || o >= SSL) ? (int)c : o;                          \
        BUF[i] = segB[o];                                                   \
        offs[i] += SL1;                                                     \
    }                                                                       \
} while (0)

#define LFRAME(ff_, BUF, MSK) do {                                          \
    const int ff = (ff_);                                                   \
    float tt[25];                                                           \
    _Pragma("unroll")                                                       \
    for (int i = 0; i < 25; ++i) {                                          \
        const float rv = ring[radr[i]];                                     \
        const float tv = rv + fmaf(BUF[i], jfv[i], dgv[i]);                 \
        bool vld = (i < nt);                                                \
        if (MSK) vld = vld && (jlo + i <= ff + 1);                          \
        tt[i] = vld ? tv : NEGF;                                            \
        radr[i] += RSTR;                                                    \
        if (radr[i] >= RWRAP) radr[i] -= RWRAP;                             \
    }                                                                       \
    float m = tt[0];                                                        \
    _Pragma("unroll")                                                       \
    for (int i = 1; i < 25; ++i) m = fmaxf(m, tt[i]);                       \
    float s = 0.f;                                                          \
    _Pragma("unroll")                                                       \
    for (int i = 0; i < 25; ++i) s += __expf(tt[i] - m);                    \
    const float m2 = __shfl_xor(m, 32);                                     \
    const float s2 = __shfl_xor(s, 32);                                     \
    const float Mw = fmaxf(m, m2);                                          \
    const float Sw = fmaf(s, __expf(m - Mw), s2 * __expf(m2 - Mw));         \
    if (h == 0) part[ff & 31][c] = make_float2(Mw, Sw);                     \
} while (0)

__launch_bounds__(256, 1)
__global__ void semicrf_fwd(const float* __restrict__ seg,
                            const float* __restrict__ trans,
                            float* __restrict__ out)
{
    const int t  = threadIdx.x;
    const int b  = blockIdx.x;
    const int c  = t & 31;
    const int h  = (t >> 5) & 1;
    const int wv = t >> 6;

    __shared__ float ring[RROWS * RSTR];        // log-beta; row (p+1)&127
    __shared__ float2 part[32][32];             // lag (M,S) partials, slot f&31
    __shared__ __align__(16) float ubuf[32];    // chain matvec broadcast
    __shared__ int cnt_s[4];                    // 0..2 lag batch done, 3 chain done

    if (t < 32) ring[t] = 0.f;                  // row 0 = beta[-1] = 0
    if (t < 4)  cnt_s[t] = -1;
    __syncthreads();                            // only barrier in the kernel

    const float* segB = seg + (size_t)b * S * S * L;
    volatile int* cntv = cnt_s;

    if (wv == 0) {
        // -------------------- chain wave --------------------
        __builtin_amdgcn_s_setprio(1);
        float E[32];
#pragma unroll
        for (int i = 0; i < 32; ++i) E[i] = __expf(trans[i * 32 + c]);
        const float diag_c = trans[c * 33];
        float dgc[14];
#pragma unroll
        for (int i = 0; i < 14; ++i) dgc[i] = diag_c * (float)(i + 1);

        // beta history: bH[k] = beta[f-1-k] at start of frame f
        float bH[14];
        bH[0] = 0.f;                            // beta[-1]
#pragma unroll
        for (int i = 1; i < 14; ++i) bH[i] = NEGF;

        // seg buffers: sO holds odd e, sE even e; index i <-> j = i+1
        float sO[15], sE[15];
        int offv[15];
#pragma unroll
        for (int i = 0; i < 15; ++i) {
            const int j = i + 1;
            int o1 = 1 * SL1 - (j - 1) * SLN + (int)c;   // e = 1
            int o2 = 2 * SL1 - (j - 1) * SLN + (int)c;   // e = 2
            o1 = o1 < (int)c ? (int)c : o1;
            o2 = o2 < (int)c ? (int)c : o2;
            sO[i] = segB[o1];
            sE[i] = segB[o2];
            offv[i] = 3 * SL1 - (j - 1) * SLN + (int)c;  // next load: e = 3
        }

        float Ma = segB[c];                     // alpha[0] as (max,sum)
        float Sa = 1.f;
        float mx = Ma;
        RED32_MAX(mx);                          // exact normalizer for frame 0
        int wadr = RSTR + (int)c;               // beta[0] -> row 1

        // partial pipeline: wait batch 0, prime pp1=partial(1), pp2=partial(2)
        {
            volatile int* cw = &cntv[0];
            int zz = 0;
            while (*cw < 0 && ++zz < SPIN_CAP) {}
            __builtin_amdgcn_fence(__ATOMIC_ACQUIRE, "workgroup", "local");
        }
        float2 pp1 = part[1][c];
        float2 pp2 = part[2][c];

        for (int f = 0; f < 508; f += 4) {
            CHAIN(f + 0, sO, false, false);
            CHAIN(f + 1, sE, true,  false);
            CHAIN(f + 2, sO, false, false);
            CHAIN(f + 3, sE, false, true);
        }
        CHAIN(508, sO, false, false);
        CHAIN(509, sE, true,  false);           // poll guard skips (512 > 508)
        CHAIN(510, sO, false, false);

        // log_z[b] = LSE_c ( Ma + log Sa ) over c (halves duplicate -> use
        // xor masks <= 16 so the reduce stays inside each 32-lane half)
        float m = Ma + __logf(Sa);
        float ss = 1.f;
#pragma unroll
        for (int mk = 1; mk <= 16; mk <<= 1) {
            const float m2 = __shfl_xor(m, mk);
            const float s2 = __shfl_xor(ss, mk);
            const float mn = fmaxf(m, m2);
            ss = ss * __expf(m - mn) + s2 * __expf(m2 - mn);
            m  = mn;
        }
        if (t == 0) out[b] = m + __logf(ss);
    } else {
        // -------------------- lag waves: j = 16..64 --------------------
        const int wl  = wv - 1;                 // 0,1,2
        const int jlo = h ? 41 : 16;
        const int nt  = h ? 24 : 25;            // valid terms this half
        const float diag_c = trans[c * 33];

        float jfv[25], dgv[25];
        int offs[25], radr[25];
        const int F0 = 4 * wl;
#pragma unroll
        for (int i = 0; i < 25; ++i) {
            const int j = jlo + i;
            jfv[i] = (float)j;
            dgv[i] = diag_c * (float)(j - 1);
            offs[i] = F0 * SL1 - (j - 1) * SLN + (int)c;
            const int row = (F0 - j + 1) & (RROWS - 1);
            radr[i] = row * RSTR + (int)c;
        }

        float bufA[25], bufB[25];
        int cdv = -1;
        int F = F0;
        LLOAD(bufA);                            // frame F
        LLOAD(bufB);                            // frame F+1
        while (F <= 508) {
            if (F >= 16) {
                const int need = F - 13;
                int zz = 0;
                while (cdv < need && ++zz < SPIN_CAP) {
                    __builtin_amdgcn_s_sleep(1); cdv = cntv[3];
                }
                __builtin_amdgcn_fence(__ATOMIC_ACQUIRE, "workgroup", "local");
            }
            if (F <= 60) {
                LFRAME(F + 0, bufA, true);  LLOAD(bufA);   // loads F+2
                LFRAME(F + 1, bufB, true);  LLOAD(bufB);   // loads F+3
                LFRAME(F + 2, bufA, true);
                LFRAME(F + 3, bufB, true);
            } else {
                LFRAME(F + 0, bufA, false); LLOAD(bufA);
                LFRAME(F + 1, bufB, false); LLOAD(bufB);
                LFRAME(F + 2, bufA, false);
                LFRAME(F + 3, bufB, false);
            }
            asm volatile("s_waitcnt lgkmcnt(0)" ::: "memory");
            if ((t & 63) == 0) cntv[wl] = F;
            // jump to next batch (F+12): offs/radr currently at F+4
#pragma unroll
            for (int i = 0; i < 25; ++i) offs[i] += 8 * SL1;
#pragma unroll
            for (int i = 0; i < 25; ++i) {
                radr[i] += 8 * RSTR;
                if (radr[i] >= RWRAP) radr[i] -= RWRAP;
            }
            F += 12;
            if (F <= 508) { LLOAD(bufA); LLOAD(bufB); }
        }
    }
}

extern "C" void kernel_launch(void* const* d_in, const int* in_sizes, int n_in,
                              void* d_out, int out_size, void* d_ws, size_t ws_size,
                              hipStream_t stream) {
    const float* seg   = (const float*)d_in[0];   // [8, 512, 512, 32] fp32
    const float* trans = (const float*)d_in[1];   // [32, 32] fp32
    float* out = (float*)d_out;                   // [8] fp32
    hipLaunchKernelGGL(semicrf_fwd, dim3(8), dim3(256), 0, stream,
                       seg, trans, out);
}